// Round 7
// baseline (395.822 us; speedup 1.0000x reference)
//
#include <hip/hip_runtime.h>

#define N_NODES 50000
#define E_EDGES 800000
#define IN_DIM  256
#define HID     128
#define HALF    64
#define OUT_DIM 2
#define NB      16        // nodes per wave-block (50000/16 = 3125 exactly)
#define SLOPE   0.01f

#define HS_STRIDE 132              // 128 + 4 pad: broadcast quads hit 16 disjoint banks
#define BUF_FLOATS (NB * HS_STRIDE)   // 2112 floats = 8448 B

// acc[c..c+7] += xv * W[k][c..c+7]
__device__ __forceinline__ void fma8(float* acc, float xv, float4 w0, float4 w1) {
    acc[0] = fmaf(xv, w0.x, acc[0]); acc[1] = fmaf(xv, w0.y, acc[1]);
    acc[2] = fmaf(xv, w0.z, acc[2]); acc[3] = fmaf(xv, w0.w, acc[3]);
    acc[4] = fmaf(xv, w1.x, acc[4]); acc[5] = fmaf(xv, w1.y, acc[5]);
    acc[6] = fmaf(xv, w1.z, acc[6]); acc[7] = fmaf(xv, w1.w, acc[7]);
}

// one k-quad of the weight panel: 8 x float4 (4 k-rows x 8 channels)
__device__ __forceinline__ void load_w8(float4* w, const float* __restrict__ W,
                                        int k, int c0) {
    w[0] = *(const float4*)(W + (size_t)(k + 0) * HID + c0);
    w[1] = *(const float4*)(W + (size_t)(k + 0) * HID + c0 + 4);
    w[2] = *(const float4*)(W + (size_t)(k + 1) * HID + c0);
    w[3] = *(const float4*)(W + (size_t)(k + 1) * HID + c0 + 4);
    w[4] = *(const float4*)(W + (size_t)(k + 2) * HID + c0);
    w[5] = *(const float4*)(W + (size_t)(k + 2) * HID + c0 + 4);
    w[6] = *(const float4*)(W + (size_t)(k + 3) * HID + c0);
    w[7] = *(const float4*)(W + (size_t)(k + 3) * HID + c0 + 4);
}

// acc[r][0..7] += buf[(gq+4r)*HS_STRIDE + k + 0..3] * w  (128 FMAs, 4 LDS b128)
__device__ __forceinline__ void fma_quad(float acc[4][8], const float4* w,
                                         const float* bufk, int gq) {
    #pragma unroll
    for (int r = 0; r < 4; r++) {
        float4 xq = *(const float4*)(bufk + (gq + 4 * r) * HS_STRIDE);
        fma8(acc[r], xq.x, w[0], w[1]);
        fma8(acc[r], xq.y, w[2], w[3]);
        fma8(acc[r], xq.z, w[4], w[5]);
        fma8(acc[r], xq.w, w[6], w[7]);
    }
}

// K-panel GEMM with register-double-buffered weights (K % 8 == 0)
__device__ __forceinline__ void gemm_db(float acc[4][8], const float* __restrict__ W,
                                        int K, const float* buf, int gq, int c0) {
    float4 wA[8], wB[8];
    load_w8(wA, W, 0, c0);
    for (int k = 0; k < K; k += 8) {
        load_w8(wB, W, k + 4, c0);
        fma_quad(acc, wA, buf + k, gq);
        if (k + 8 < K) load_w8(wA, W, k + 8, c0);
        fma_quad(acc, wB, buf + k + 4, gq);
    }
}

// ---------------------------------------------------------------- degree ----
__global__ void zero_int_kernel(int* __restrict__ p, int n) {
    int i = blockIdx.x * blockDim.x + threadIdx.x;
    if (i < n) p[i] = 0;
}

// cnt histogram + per-edge ticket (rank within its target bucket)
__global__ void deg_ticket_kernel(const int* __restrict__ col,
                                  int* __restrict__ cnt, int* __restrict__ ticket) {
    int e = blockIdx.x * blockDim.x + threadIdx.x;
    if (e < E_EDGES) ticket[e] = atomicAdd(&cnt[col[e]], 1);
}

// Exclusive scan of cnt[0..N) -> row_start[0..N], single 1024-thread block.
__global__ __launch_bounds__(1024) void scan_kernel(
    const int* __restrict__ cnt, int* __restrict__ row_start)
{
    __shared__ int sums[1024];
    const int T  = 1024;
    const int t  = threadIdx.x;
    const int CH = (N_NODES + T - 1) / T;   // 49
    const int base = t * CH;

    int s = 0;
    for (int k = 0; k < CH; k++) {
        int i = base + k;
        if (i < N_NODES) s += cnt[i];
    }
    sums[t] = s;
    __syncthreads();
    for (int off = 1; off < T; off <<= 1) {
        int v = (t >= off) ? sums[t - off] : 0;
        __syncthreads();
        sums[t] += v;
        __syncthreads();
    }
    int run = (t == 0) ? 0 : sums[t - 1];
    for (int k = 0; k < CH; k++) {
        int i = base + k;
        if (i < N_NODES) { row_start[i] = run; run += cnt[i]; }
    }
    if (t == T - 1) row_start[N_NODES] = run;
}

// atomic-free fill using tickets
__global__ void fill_kernel(const int* __restrict__ ei,
                            const int* __restrict__ row_start,
                            const int* __restrict__ ticket,
                            int* __restrict__ csr_src)
{
    int e = blockIdx.x * blockDim.x + threadIdx.x;
    if (e >= E_EDGES) return;
    int j = ei[e];              // source
    int i = ei[E_EDGES + e];    // target
    csr_src[row_start[i] + ticket[e]] = j;
}

// ------------------------------------------------------------- node phase ---
// One 64-lane wave per 16 nodes. lane = (gq = l>>4, m = l&15):
// owns channels c0=8m..8m+7 and nodes n = gq + 4r (r=0..3).
// Weights register-double-buffered; 8.45 KB LDS overlaid x-half -> h -> s.
__global__ __launch_bounds__(64, 3) void node_phase_kernel(
    const float* __restrict__ x,
    const float* __restrict__ W_in,    const float* __restrict__ b_in,
    const float* __restrict__ W_nor,   const float* __restrict__ b_nor,
    const float* __restrict__ W_abnor, const float* __restrict__ b_abnor,
    const float* __restrict__ W_att,   const float* __restrict__ b_att,
    const float* __restrict__ v_att,
    const int* __restrict__ cnt,
    float* __restrict__ u)
{
    __shared__ __align__(16) float buf[BUF_FLOATS];

    const int l     = threadIdx.x;
    const int gq    = l >> 4;
    const int m     = l & 15;
    const int c0    = m * 8;
    const int node0 = blockIdx.x * NB;
    const float* xrow = x + (size_t)node0 * IN_DIM;

    // ---- h = leaky_relu(x @ W_in + b_in), k staged in two 128-halves ----
    float a0[4][8];
    {
        float4 b0 = *(const float4*)(b_in + c0);
        float4 b1 = *(const float4*)(b_in + c0 + 4);
        #pragma unroll
        for (int r = 0; r < 4; r++) {
            a0[r][0] = b0.x; a0[r][1] = b0.y; a0[r][2] = b0.z; a0[r][3] = b0.w;
            a0[r][4] = b1.x; a0[r][5] = b1.y; a0[r][6] = b1.z; a0[r][7] = b1.w;
        }
    }
    for (int half = 0; half < 2; half++) {
        const float* Wh = W_in + (size_t)half * 128 * HID;
        float4 wA[8], wB[8];
        load_w8(wA, Wh, 0, c0);          // in flight during staging
        #pragma unroll
        for (int it = 0; it < NB * 128 / 4 / 64; it++) {   // 8
            int i = it * 64 + l;
            int n = i >> 5, kq = i & 31;
            float4 v = *(const float4*)(xrow + (size_t)n * IN_DIM + half * 128 + kq * 4);
            *(float4*)&buf[n * HS_STRIDE + kq * 4] = v;
        }
        __syncthreads();
        for (int k = 0; k < 128; k += 8) {
            load_w8(wB, Wh, k + 4, c0);
            fma_quad(a0, wA, buf + k, gq);
            if (k + 8 < 128) load_w8(wA, Wh, k + 8, c0);
            fma_quad(a0, wB, buf + k + 4, gq);
        }
        __syncthreads();   // this half consumed
    }

    // ---- h -> buf (leaky relu) ----
    #pragma unroll
    for (int r = 0; r < 4; r++) {
        int n = gq + 4 * r;
        float4 h0, h1;
        float v;
        v = a0[r][0]; h0.x = v > 0.f ? v : SLOPE * v;
        v = a0[r][1]; h0.y = v > 0.f ? v : SLOPE * v;
        v = a0[r][2]; h0.z = v > 0.f ? v : SLOPE * v;
        v = a0[r][3]; h0.w = v > 0.f ? v : SLOPE * v;
        v = a0[r][4]; h1.x = v > 0.f ? v : SLOPE * v;
        v = a0[r][5]; h1.y = v > 0.f ? v : SLOPE * v;
        v = a0[r][6]; h1.z = v > 0.f ? v : SLOPE * v;
        v = a0[r][7]; h1.w = v > 0.f ? v : SLOPE * v;
        *(float4*)&buf[n * HS_STRIDE + c0]     = h0;
        *(float4*)&buf[n * HS_STRIDE + c0 + 4] = h1;
    }
    __syncthreads();

    // ---- x_nor = h[:,:64] @ W_nor + b_nor (separate pass) ----
    float xn[4][8];
    {
        float4 b0 = *(const float4*)(b_nor + c0);
        float4 b1 = *(const float4*)(b_nor + c0 + 4);
        #pragma unroll
        for (int r = 0; r < 4; r++) {
            xn[r][0] = b0.x; xn[r][1] = b0.y; xn[r][2] = b0.z; xn[r][3] = b0.w;
            xn[r][4] = b1.x; xn[r][5] = b1.y; xn[r][6] = b1.z; xn[r][7] = b1.w;
        }
    }
    gemm_db(xn, W_nor, HALF, buf, gq, c0);

    // ---- x_abnor = h[:,64:] @ W_abnor + b_abnor ----
    float xa[4][8];
    {
        float4 b0 = *(const float4*)(b_abnor + c0);
        float4 b1 = *(const float4*)(b_abnor + c0 + 4);
        #pragma unroll
        for (int r = 0; r < 4; r++) {
            xa[r][0] = b0.x; xa[r][1] = b0.y; xa[r][2] = b0.z; xa[r][3] = b0.w;
            xa[r][4] = b1.x; xa[r][5] = b1.y; xa[r][6] = b1.z; xa[r][7] = b1.w;
        }
    }
    gemm_db(xa, W_abnor, HALF, buf + HALF, gq, c0);
    __syncthreads();   // h consumed

    // ---- s = xn + xa -> buf ----
    #pragma unroll
    for (int r = 0; r < 4; r++) {
        int n = gq + 4 * r;
        float4 s0, s1;
        s0.x = xn[r][0] + xa[r][0]; s0.y = xn[r][1] + xa[r][1];
        s0.z = xn[r][2] + xa[r][2]; s0.w = xn[r][3] + xa[r][3];
        s1.x = xn[r][4] + xa[r][4]; s1.y = xn[r][5] + xa[r][5];
        s1.z = xn[r][6] + xa[r][6]; s1.w = xn[r][7] + xa[r][7];
        *(float4*)&buf[n * HS_STRIDE + c0]     = s0;
        *(float4*)&buf[n * HS_STRIDE + c0 + 4] = s1;
    }
    __syncthreads();

    // ---- t = s @ W_att + b_att ----
    float t[4][8];
    {
        float4 b0 = *(const float4*)(b_att + c0);
        float4 b1 = *(const float4*)(b_att + c0 + 4);
        #pragma unroll
        for (int r = 0; r < 4; r++) {
            t[r][0] = b0.x; t[r][1] = b0.y; t[r][2] = b0.z; t[r][3] = b0.w;
            t[r][4] = b1.x; t[r][5] = b1.y; t[r][6] = b1.z; t[r][7] = b1.w;
        }
    }
    gemm_db(t, W_att, HID, buf, gq, c0);

    // ---- alpha = sigmoid(sum_c tanh(t)*v): reduce over 16 ch-group lanes ----
    float gg[4];
    {
        float4 v0 = *(const float4*)(v_att + c0);
        float4 v1 = *(const float4*)(v_att + c0 + 4);
        #pragma unroll
        for (int r = 0; r < 4; r++) {
            gg[r] = tanhf(t[r][0]) * v0.x + tanhf(t[r][1]) * v0.y
                  + tanhf(t[r][2]) * v0.z + tanhf(t[r][3]) * v0.w
                  + tanhf(t[r][4]) * v1.x + tanhf(t[r][5]) * v1.y
                  + tanhf(t[r][6]) * v1.z + tanhf(t[r][7]) * v1.w;
        }
    }
    #pragma unroll
    for (int msk = 8; msk >= 1; msk >>= 1) {
        #pragma unroll
        for (int r = 0; r < 4; r++) gg[r] += __shfl_xor(gg[r], msk, 64);
    }

    #pragma unroll
    for (int r = 0; r < 4; r++) {
        int n = gq + 4 * r;
        float alpha = 1.f / (1.f + expf(-gg[r]));
        float beta  = 1.f - alpha;
        float dinv  = rsqrtf((float)cnt[node0 + n] + 1.0f);  // +1 self loop
        float4 o0, o1;
        o0.x = dinv * (alpha * xn[r][0] + beta * xa[r][0]);
        o0.y = dinv * (alpha * xn[r][1] + beta * xa[r][1]);
        o0.z = dinv * (alpha * xn[r][2] + beta * xa[r][2]);
        o0.w = dinv * (alpha * xn[r][3] + beta * xa[r][3]);
        o1.x = dinv * (alpha * xn[r][4] + beta * xa[r][4]);
        o1.y = dinv * (alpha * xn[r][5] + beta * xa[r][5]);
        o1.z = dinv * (alpha * xn[r][6] + beta * xa[r][6]);
        o1.w = dinv * (alpha * xn[r][7] + beta * xa[r][7]);
        *(float4*)(u + (size_t)(node0 + n) * HID + c0)     = o0;
        *(float4*)(u + (size_t)(node0 + n) * HID + c0 + 4) = o1;
    }
}

// ------------------------------------------------------------- edge phase ---
// One wave per target node: acc[i] = u[i] + sum_{j in in(i)} u[j]
__global__ __launch_bounds__(256) void gather_kernel(
    const int* __restrict__ row_start, const int* __restrict__ csr_src,
    const float* __restrict__ u, float* __restrict__ acc)
{
    int node = blockIdx.x * 4 + (threadIdx.x >> 6);
    int lane = threadIdx.x & 63;
    if (node >= N_NODES) return;

    float2 s = *(const float2*)(u + (size_t)node * HID + lane * 2);
    int b = row_start[node], e = row_start[node + 1];
    int p = b;
    for (; p + 8 <= e; p += 8) {
        int j0 = csr_src[p + 0], j1 = csr_src[p + 1];
        int j2 = csr_src[p + 2], j3 = csr_src[p + 3];
        int j4 = csr_src[p + 4], j5 = csr_src[p + 5];
        int j6 = csr_src[p + 6], j7 = csr_src[p + 7];
        float2 v0 = *(const float2*)(u + (size_t)j0 * HID + lane * 2);
        float2 v1 = *(const float2*)(u + (size_t)j1 * HID + lane * 2);
        float2 v2 = *(const float2*)(u + (size_t)j2 * HID + lane * 2);
        float2 v3 = *(const float2*)(u + (size_t)j3 * HID + lane * 2);
        float2 v4 = *(const float2*)(u + (size_t)j4 * HID + lane * 2);
        float2 v5 = *(const float2*)(u + (size_t)j5 * HID + lane * 2);
        float2 v6 = *(const float2*)(u + (size_t)j6 * HID + lane * 2);
        float2 v7 = *(const float2*)(u + (size_t)j7 * HID + lane * 2);
        s.x += v0.x + v1.x + v2.x + v3.x + v4.x + v5.x + v6.x + v7.x;
        s.y += v0.y + v1.y + v2.y + v3.y + v4.y + v5.y + v6.y + v7.y;
    }
    for (; p < e; p++) {
        int j = csr_src[p];
        float2 v = *(const float2*)(u + (size_t)j * HID + lane * 2);
        s.x += v.x; s.y += v.y;
    }
    *(float2*)(acc + (size_t)node * HID + lane * 2) = s;
}

// ------------------------------------------------------------ final phase ---
// Same tiling; W_upd register-double-buffered; buf overlaid as -> us.
__global__ __launch_bounds__(64, 3) void final_phase_kernel(
    const float* __restrict__ acc, const int* __restrict__ cnt,
    const float* __restrict__ W_upd, const float* __restrict__ b_upd,
    const float* __restrict__ W_cls, const float* __restrict__ b_cls,
    float* __restrict__ out)
{
    __shared__ __align__(16) float buf[BUF_FLOATS];

    const int l     = threadIdx.x;
    const int gq    = l >> 4;
    const int m     = l & 15;
    const int c0    = m * 8;
    const int node0 = blockIdx.x * NB;
    const float* arow = acc + (size_t)node0 * HID;

    float4 wA[8];
    load_w8(wA, W_upd, 0, c0);          // in flight during staging

    // stage acc prescaled by dinv
    #pragma unroll
    for (int it = 0; it < NB * HID / 4 / 64; it++) {   // 8
        int i = it * 64 + l;
        int n = i >> 5, kq = i & 31;
        float d = rsqrtf((float)cnt[node0 + n] + 1.0f);
        float4 v = *(const float4*)(arow + (size_t)i * 4);
        v.x *= d; v.y *= d; v.z *= d; v.w *= d;
        *(float4*)&buf[n * HS_STRIDE + kq * 4] = v;
    }
    __syncthreads();

    float up[4][8];
    {
        float4 b0 = *(const float4*)(b_upd + c0);
        float4 b1 = *(const float4*)(b_upd + c0 + 4);
        #pragma unroll
        for (int r = 0; r < 4; r++) {
            up[r][0] = b0.x; up[r][1] = b0.y; up[r][2] = b0.z; up[r][3] = b0.w;
            up[r][4] = b1.x; up[r][5] = b1.y; up[r][6] = b1.z; up[r][7] = b1.w;
        }
    }
    {
        float4 wB[8];
        for (int k = 0; k < HID; k += 8) {
            load_w8(wB, W_upd, k + 4, c0);
            fma_quad(up, wA, buf + k, gq);
            if (k + 8 < HID) load_w8(wA, W_upd, k + 8, c0);
            fma_quad(up, wB, buf + k + 4, gq);
        }
    }
    __syncthreads();   // as consumed; buf becomes us

    #pragma unroll
    for (int r = 0; r < 4; r++) {
        int n = gq + 4 * r;
        float4 u0, u1;
        float v;
        v = up[r][0]; u0.x = v > 0.f ? v : SLOPE * v;
        v = up[r][1]; u0.y = v > 0.f ? v : SLOPE * v;
        v = up[r][2]; u0.z = v > 0.f ? v : SLOPE * v;
        v = up[r][3]; u0.w = v > 0.f ? v : SLOPE * v;
        v = up[r][4]; u1.x = v > 0.f ? v : SLOPE * v;
        v = up[r][5]; u1.y = v > 0.f ? v : SLOPE * v;
        v = up[r][6]; u1.z = v > 0.f ? v : SLOPE * v;
        v = up[r][7]; u1.w = v > 0.f ? v : SLOPE * v;
        *(float4*)&buf[n * HS_STRIDE + c0]     = u0;
        *(float4*)&buf[n * HS_STRIDE + c0 + 4] = u1;
    }
    __syncthreads();

    if (l < NB * OUT_DIM) {
        int n = l >> 1, o = l & 1;
        float s = b_cls[o];
        for (int k = 0; k < HID; k++)
            s = fmaf(buf[n * HS_STRIDE + k], W_cls[k * OUT_DIM + o], s);
        out[(size_t)(node0 + n) * OUT_DIM + o] = s;
    }
}

// ------------------------------------------------------------------ launch --
extern "C" void kernel_launch(void* const* d_in, const int* in_sizes, int n_in,
                              void* d_out, int out_size, void* d_ws, size_t ws_size,
                              hipStream_t stream)
{
    const float* x       = (const float*)d_in[0];
    const int*   ei      = (const int*)  d_in[1];   // [2, E] int32
    const float* W_in    = (const float*)d_in[2];
    const float* b_in    = (const float*)d_in[3];
    const float* W_nor   = (const float*)d_in[4];
    const float* b_nor   = (const float*)d_in[5];
    const float* W_abnor = (const float*)d_in[6];
    const float* b_abnor = (const float*)d_in[7];
    const float* W_att   = (const float*)d_in[8];
    const float* b_att   = (const float*)d_in[9];
    const float* v_att   = (const float*)d_in[10];
    const float* W_upd   = (const float*)d_in[11];
    const float* b_upd   = (const float*)d_in[12];
    const float* W_cls   = (const float*)d_in[13];
    const float* b_cls   = (const float*)d_in[14];
    float* out = (float*)d_out;

    // workspace: cnt[N] | row_start[N+1] | csr_src[E] | u[N*HID] | acc[N*HID]
    // ticket[E] aliases acc (acc is only written by gather, after fill).
    int*   cnt       = (int*)d_ws;
    int*   row_start = cnt + N_NODES;
    int*   csr_src   = row_start + (N_NODES + 1);
    float* u         = (float*)(csr_src + E_EDGES);
    float* acc       = u + (size_t)N_NODES * HID;
    int*   ticket    = (int*)acc;

    zero_int_kernel<<<(N_NODES + 255) / 256, 256, 0, stream>>>(cnt, N_NODES);
    deg_ticket_kernel<<<(E_EDGES + 255) / 256, 256, 0, stream>>>(ei + E_EDGES, cnt, ticket);
    scan_kernel<<<1, 1024, 0, stream>>>(cnt, row_start);
    fill_kernel<<<(E_EDGES + 255) / 256, 256, 0, stream>>>(ei, row_start, ticket, csr_src);
    node_phase_kernel<<<N_NODES / NB, 64, 0, stream>>>(
        x, W_in, b_in, W_nor, b_nor, W_abnor, b_abnor,
        W_att, b_att, v_att, cnt, u);
    gather_kernel<<<(N_NODES + 3) / 4, 256, 0, stream>>>(row_start, csr_src, u, acc);
    final_phase_kernel<<<N_NODES / NB, 64, 0, stream>>>(
        acc, cnt, W_upd, b_upd, W_cls, b_cls, out);
}